// Round 2
// baseline (267.267 us; speedup 1.0000x reference)
//
#include <hip/hip_runtime.h>
#include <hip/hip_bf16.h>
#include <hip/hip_fp16.h>

// INPUTS/OUTPUT ARE FLOAT32 (R1/R3/R4 NaN'd reading them as bf16).
// R18: cut trans-pipe ops 65->33/iter via stable-sigmoid + VALU Newton rcp.
//      R17 (NaN) relied on elementwise_min clamping exp2 args to keep
//      d=1+2^a finite for NR; sigmoid preacts reach ~±300 so any clamp
//      failure -> inf -> NR NaN. R18 is domain-safe BY CONSTRUCTION:
//      E = 2^(-|v|*log2e) in (0,1], d = 1+E in (1,2] always; NR bit-seed
//      converges monotonically (g0 < 1/d). sigmoid = 0.5+copysign(r-.5, v)
//      (v_bfi_b32, no branch). Trans 1040->528 cyc/iter; VALU ~590 cyc/iter;
//      2 waves/SIMD co-issue trans||VALU -> predict edge ~70us.
// PERF NOTES (session summary):
//  - R5: forced low VGPR budget -> scratch spills, 2.6x slower. Keep (256,2).
//  - R11/R13/R16: three different inner-loop mixes all = ~145.5 us edge ->
//    trans-pipe instruction floor at that op mix (~1.08G trans lane-ops).
//  - Occupancy levers ALL exhausted: bounds(2/4/none), grid x2, LDS /2,
//    weights->LDS, 512-thread blocks — none raise real residency.
//  - Node/memset/launch overhead (~67 us) invariant to node restructure.

#define NTOT 2048
#define MTOT 2048
#define MSPLIT 32
#define MCHUNK 64   // == per-block m range: single staging chunk
#define NODE_ROWS 4 // rows per node block (1 per wave)

typedef _Float16 f16x8 __attribute__((ext_vector_type(8)));
typedef float f32x4  __attribute__((ext_vector_type(4)));
typedef float f32x2  __attribute__((ext_vector_type(2)));
typedef int   i32x4  __attribute__((ext_vector_type(4)));

// exp(x) = 2^(x*log2e); sigmoid(x) = 1/(1+2^(-x*log2e))
#define NL2E (-1.4426950408889634f)
// exp(-d2/5) = 2^(d2 * -log2e/5)
#define C1E  (-0.2885390081777927f)

__device__ __forceinline__ float fast_exp2(float x) {
#if __has_builtin(__builtin_amdgcn_exp2f)
  return __builtin_amdgcn_exp2f(x);
#else
  return __exp2f(x);
#endif
}
__device__ __forceinline__ float fast_rcp(float x) {
#if __has_builtin(__builtin_amdgcn_rcpf)
  return __builtin_amdgcn_rcpf(x);
#else
  return 1.0f / x;
#endif
}
__device__ __forceinline__ float fast_rsq(float x) {
#if __has_builtin(__builtin_amdgcn_rsqf)
  return __builtin_amdgcn_rsqf(x);
#else
  return rsqrtf(x);
#endif
}
__device__ __forceinline__ f32x2 pk_fma(f32x2 a, f32x2 b, f32x2 c) {
  return __builtin_elementwise_fma(a, b, c);
}

// Packed reciprocal WITHOUT the trans pipe, for d in (1, 2] ONLY:
// bit-trick seed (underestimates, ~5% rel err) + 2 Newton steps
// (-> ~2.5e-3 -> ~6e-6 rel; monotone from below, cannot diverge/NaN).
// 2x v_sub_u32 + 2x v_pk_fma_f32 + 2x v_pk_mul_f32 = 6 VALU / 2 values.
__device__ __forceinline__ f32x2 rcp_nr2(f32x2 d) {
  const unsigned ux = 0x7EF311C3u - __builtin_bit_cast(unsigned, d.x);
  const unsigned uy = 0x7EF311C3u - __builtin_bit_cast(unsigned, d.y);
  f32x2 g = {__builtin_bit_cast(float, ux), __builtin_bit_cast(float, uy)};
  const f32x2 two = {2.f, 2.f};
  g = g * pk_fma(-d, g, two);
  g = g * pk_fma(-d, g, two);
  return g;
}

// Stable sigmoid on a pair: E = 2^(-|v|*log2e) in (0,1], r = 1/(1+E) in
// [0.5,1), sigmoid = 0.5 + copysign(r-0.5, v). 2 trans + ~13 VALU / pair;
// no clamp needed, no inf/NaN possible for finite v.
__device__ __forceinline__ f32x2 stable_sigmoid2(f32x2 v, f32x2 nl2e2,
                                                 f32x2 one2) {
  const f32x2 av = {__builtin_fabsf(v.x), __builtin_fabsf(v.y)};
  const f32x2 q = av * nl2e2;              // <= 0
  f32x2 e;
  e.x = fast_exp2(q.x);
  e.y = fast_exp2(q.y);                    // (0, 1]
  const f32x2 r = rcp_nr2(e + one2);       // d in (1, 2]
  return f32x2{0.5f + __builtin_copysignf(r.x - 0.5f, v.x),
               0.5f + __builtin_copysignf(r.y - 0.5f, v.y)};
}

// pack two f32 -> two f16 (RTZ) in one u32 via v_cvt_pkrtz_f16_f32 (1 instr).
__device__ __forceinline__ unsigned pack_f16_rtz(float lo, float hi) {
#if __has_builtin(__builtin_amdgcn_cvt_pkrtz)
  auto p = __builtin_amdgcn_cvt_pkrtz(lo, hi);  // __fp16 ext_vector(2)
  return __builtin_bit_cast(unsigned, p);
#else
  union { _Float16 h; unsigned short u; } a, b;
  a.h = (_Float16)lo; b.h = (_Float16)hi;
  return (unsigned)a.u | ((unsigned)b.u << 16);
#endif
}

// ---------------------------------------------------------------------------
// Edge phase: per wave, 16 n-rows; loop over this block's 64-m range.
// dist-arg via d2 expansion (4 slots); layer1+silu in packed f32; A-frags
// packed with cvt_pkrtz; mfma_16x16x32_f16; sigmoid f32; atomicAdd partials.
// Grid: (NTOT/64) * MSPLIT = 1024 blocks of 256.
// ---------------------------------------------------------------------------
__global__ __launch_bounds__(256, 2)
void edge_kernel(const float* __restrict__ h_l,
                 const float* __restrict__ x_l,
                 const float* __restrict__ h_r,
                 const float* __restrict__ x_r,
                 const float* __restrict__ W1,
                 const float* __restrict__ b1,
                 const float* __restrict__ W2,
                 const float* __restrict__ b2,
                 float* __restrict__ num_g,
                 float* __restrict__ den_g) {
  // hrT[ms][l15*4 + c] = h_r[m][c*16 + l15]  (per-lane float4 -> ds_read_b128)
  __shared__ float hrT[MCHUNK][64];   // 16 KB
  // xr_s[ms] = {xrC0, xrC1, xrC2, srC, rp0, rp1, rp2, pad}
  //   xrC = x_r * (-2*C1E), srC = |x_r|^2 * C1E
  __shared__ float xr_s[MCHUNK][8];   // 2 KB

  const int tid  = threadIdx.x;
  const int wave = tid >> 6;
  const int lane = tid & 63;
  const int l15  = lane & 15;
  const int quad = lane >> 4;

  const int nblk   = blockIdx.x / MSPLIT;
  const int msplit = blockIdx.x % MSPLIT;
  const int n0     = nblk * 64 + wave * 16;
  const int mBase  = msplit * MCHUNK;

  // per-lane A-row n
  const int nA = n0 + l15;
  const float xl0 = x_l[nA * 3 + 0];
  const float xl1 = x_l[nA * 3 + 1];
  const float xl2 = x_l[nA * 3 + 2];
  const float slC = fmaf(xl2, xl2, fmaf(xl1, xl1, xl0 * xl0)) * C1E;
  const float lp0 = h_l[nA * 64 + 61];
  const float lp1 = h_l[nA * 64 + 62];
  const float lp2 = h_l[nA * 64 + 63];

  // layer-1 weights as f32 pairs over j (this lane's 16 h1 cols:
  // h1 = quad*8 + j for j<8, 32 + quad*8 + (j-8) for j>=8)
  f32x2 w1d2[8], w1h2[8], w1y2[8], b1p2[8];
#pragma unroll
  for (int p = 0; p < 8; ++p) {
    const int j0 = 2 * p, j1 = 2 * p + 1;
    const int hA = (j0 < 8) ? (quad * 8 + j0) : (32 + quad * 8 + (j0 - 8));
    const int hB = (j1 < 8) ? (quad * 8 + j1) : (32 + quad * 8 + (j1 - 8));
    w1d2[p] = f32x2{W1[0 * 64 + hA], W1[0 * 64 + hB]};
    w1h2[p] = f32x2{W1[1 * 64 + hA], W1[1 * 64 + hB]};
    w1y2[p] = f32x2{W1[2 * 64 + hA], W1[2 * 64 + hB]};
    // edge_raw[3] == 1 -> fold W1 row 3 into bias
    b1p2[p] = f32x2{b1[hA] + W1[3 * 64 + hA], b1[hB] + W1[3 * 64 + hB]};
  }

  // W2 B-frags (f16): B[k = half*32 + quad*8 + j][col = c*16 + l15]
  f16x8 Bfrag[4][2];
#pragma unroll
  for (int c = 0; c < 4; ++c) {
#pragma unroll
    for (int h = 0; h < 2; ++h) {
      f16x8 f;
#pragma unroll
      for (int j = 0; j < 8; ++j) {
        const int k = h * 32 + quad * 8 + j;
        f[j] = (_Float16)W2[k * 64 + c * 16 + l15];
      }
      Bfrag[c][h] = f;
    }
  }

  // b2 (plain; added to MFMA acc pre-sigmoid)
  f32x2 b2c2[4];
#pragma unroll
  for (int c = 0; c < 4; ++c) {
    const float v = b2[c * 16 + l15];
    b2c2[c] = f32x2{v, v};
  }

  // stage h_r chunk (transposed groups of 4) + precomputed xr terms
  for (int idx = tid; idx < MCHUNK * 64; idx += 256) {
    const int mm = idx >> 6, w = idx & 63;
    const int i = w >> 2, c = w & 3;
    hrT[mm][w] = h_r[(mBase + mm) * 64 + c * 16 + i];
  }
  if (tid < MCHUNK) {
    const int m = mBase + tid;
    const float a0 = x_r[m * 3 + 0], a1 = x_r[m * 3 + 1], a2 = x_r[m * 3 + 2];
    const float r0 = h_r[m * 64 + 61], r1 = h_r[m * 64 + 62], r2 = h_r[m * 64 + 63];
    xr_s[tid][0] = a0 * (-2.0f * C1E);
    xr_s[tid][1] = a1 * (-2.0f * C1E);
    xr_s[tid][2] = a2 * (-2.0f * C1E);
    xr_s[tid][3] = fmaf(a2, a2, fmaf(a1, a1, a0 * a0)) * C1E;
    xr_s[tid][4] = r0;
    xr_s[tid][5] = r1;
    xr_s[tid][6] = r2;
    xr_s[tid][7] = 0.f;
  }

  const f32x4 zero4 = {0.f, 0.f, 0.f, 0.f};
  const f32x2 one2 = {1.f, 1.f};
  const f32x2 nl2e2 = {NL2E, NL2E};
  f32x2 numr2[4][2], denr2[4][2];
#pragma unroll
  for (int c = 0; c < 4; ++c)
#pragma unroll
    for (int h = 0; h < 2; ++h) {
      numr2[c][h] = f32x2{0.f, 0.f};
      denr2[c][h] = f32x2{0.f, 0.f};
    }

  __syncthreads();

#pragma unroll 2
  for (int ms = 0; ms < MCHUNK; ++ms) {
    // dist = exp2(C1E*(|xl|^2 + |xr|^2 - 2 xl.xr)) — 4 slots + exp
    const f32x4 xa = *(const f32x4*)&xr_s[ms][0];   // xrC0 xrC1 xrC2 srC
    const f32x4 xb = *(const f32x4*)&xr_s[ms][4];   // rp0 rp1 rp2 pad
    const float arg = fmaf(xl0, xa[0], fmaf(xl1, xa[1], fmaf(xl2, xa[2], slC + xa[3])));
    const float dist = fast_exp2(arg);
    const float hb = fmaf(lp0, xb[1], lp1 * xb[0]);
    const float hy = lp2 * xb[2];
    const f32x2 distv = {dist, dist};
    const f32x2 hbv = {hb, hb};
    const f32x2 hyv = {hy, hy};

    // layer 1 + silu, packed f32, A-frag element order.
    // silu(t) = t * stable_sigmoid(t): exp2 on trans pipe, rcp on VALU pipe.
    f32x2 s2[8];
#pragma unroll
    for (int p = 0; p < 8; ++p) {
      const f32x2 t2 = pk_fma(distv, w1d2[p],
                       pk_fma(hbv, w1h2[p],
                       pk_fma(hyv, w1y2[p], b1p2[p])));
      const f32x2 w2 = stable_sigmoid2(t2, nl2e2, one2);
      s2[p] = t2 * w2;
    }
    i32x4 p0, p1;
    p0.x = pack_f16_rtz(s2[0].x, s2[0].y);  p0.y = pack_f16_rtz(s2[1].x, s2[1].y);
    p0.z = pack_f16_rtz(s2[2].x, s2[2].y);  p0.w = pack_f16_rtz(s2[3].x, s2[3].y);
    p1.x = pack_f16_rtz(s2[4].x, s2[4].y);  p1.y = pack_f16_rtz(s2[5].x, s2[5].y);
    p1.z = pack_f16_rtz(s2[6].x, s2[6].y);  p1.w = pack_f16_rtz(s2[7].x, s2[7].y);
    const f16x8 A0 = __builtin_bit_cast(f16x8, p0);
    const f16x8 A1 = __builtin_bit_cast(f16x8, p1);

    f32x4 acc[4];
#pragma unroll
    for (int c = 0; c < 4; ++c) {
      acc[c] = __builtin_amdgcn_mfma_f32_16x16x32_f16(A0, Bfrag[c][0], zero4, 0, 0, 0);
      acc[c] = __builtin_amdgcn_mfma_f32_16x16x32_f16(A1, Bfrag[c][1], acc[c], 0, 0, 0);
    }

    // sigmoid + accumulate (f32, r-pairs packed).
    // lane holds e[n = n0+quad*4+r][h2 = c*16+l15]; hrv per c via one b128.
    const f32x4 hrv4 = *(const f32x4*)&hrT[ms][l15 * 4];
#pragma unroll
    for (int c = 0; c < 4; ++c) {
      const f32x2 hrv2 = {hrv4[c], hrv4[c]};
#pragma unroll
      for (int h = 0; h < 2; ++h) {
        const f32x2 v2 = f32x2{acc[c][2 * h], acc[c][2 * h + 1]} + b2c2[c];
        const f32x2 w2 = stable_sigmoid2(v2, nl2e2, one2);
        numr2[c][h] = pk_fma(w2, hrv2, numr2[c][h]);
        denr2[c][h] = denr2[c][h] + w2;
      }
    }
  }

#pragma unroll
  for (int c = 0; c < 4; ++c)
#pragma unroll
    for (int h = 0; h < 2; ++h)
#pragma unroll
      for (int k = 0; k < 2; ++k) {
        const int r = 2 * h + k;
        const int n = n0 + quad * 4 + r;
        const int h2 = c * 16 + l15;
        atomicAdd(&num_g[n * 64 + h2], k ? numr2[c][h].y : numr2[c][h].x);
        atomicAdd(&den_g[n * 64 + h2], k ? denr2[c][h].y : denr2[c][h].x);
      }
}

// ---------------------------------------------------------------------------
// Node phase: NODE_ROWS rows per block (wave-local, no inner barriers).
// h_agg = num/(den+1e-6); z = cat(h_l,h_agg)@Wn1 + bn1 -> LN -> silu ->
// @Wn2 + bn2; out = h_l + z. Grid: NTOT/NODE_ROWS blocks of 256.
// ---------------------------------------------------------------------------
__global__ __launch_bounds__(256)
void node_kernel(const float* __restrict__ h_l,
                 const float* __restrict__ num_g,
                 const float* __restrict__ den_g,
                 const float* __restrict__ Wn1,
                 const float* __restrict__ bn1,
                 const float* __restrict__ ln_g,
                 const float* __restrict__ ln_b,
                 const float* __restrict__ Wn2,
                 const float* __restrict__ bn2,
                 float* __restrict__ out) {
  __shared__ float Wn1_s[128 * 64];
  __shared__ float Wn2_s[64 * 64];
  __shared__ float xbuf[4][128];
  __shared__ float zbuf[4][64];

  const int tid = threadIdx.x;
  for (int i = tid; i < 128 * 64; i += 256) Wn1_s[i] = Wn1[i];
  for (int i = tid; i < 64 * 64; i += 256) Wn2_s[i] = Wn2[i];

  const int wave = tid >> 6, lane = tid & 63;

  __syncthreads();

#pragma unroll 1
  for (int it = 0; it < NODE_ROWS / 4; ++it) {
    const int row = blockIdx.x * NODE_ROWS + it * 4 + wave;

    const float hl = h_l[row * 64 + lane];
    const float dn = den_g[row * 64 + lane] + 1e-6f;
    const float hagg = num_g[row * 64 + lane] * fast_rcp(dn);
    xbuf[wave][lane] = hl;
    xbuf[wave][64 + lane] = hagg;

    float t = bn1[lane];
#pragma unroll 8
    for (int k = 0; k < 128; ++k) t = fmaf(xbuf[wave][k], Wn1_s[k * 64 + lane], t);

    float s1 = t, s2 = t * t;
#pragma unroll
    for (int off = 32; off; off >>= 1) {
      s1 += __shfl_xor(s1, off);
      s2 += __shfl_xor(s2, off);
    }
    const float mu = s1 * 0.015625f;
    const float var = fmaf(s2, 0.015625f, -mu * mu);
    const float rs = fast_rsq(var + 1e-5f);
    const float zn = fmaf((t - mu) * rs, ln_g[lane], ln_b[lane]);
    const float sz = zn * fast_rcp(1.0f + fast_exp2(zn * NL2E));  // silu
    zbuf[wave][lane] = sz;

    float o = bn2[lane];
#pragma unroll 8
    for (int k = 0; k < 64; ++k) o = fmaf(zbuf[wave][k], Wn2_s[k * 64 + lane], o);

    out[row * 64 + lane] = hl + o;
  }
}

extern "C" void kernel_launch(void* const* d_in, const int* in_sizes, int n_in,
                              void* d_out, int out_size, void* d_ws, size_t ws_size,
                              hipStream_t stream) {
  const float* h_l = (const float*)d_in[0];
  const float* x_l = (const float*)d_in[1];
  const float* h_r = (const float*)d_in[2];
  const float* x_r = (const float*)d_in[3];
  const float* W1  = (const float*)d_in[4];
  const float* b1  = (const float*)d_in[5];
  const float* W2  = (const float*)d_in[6];
  const float* b2  = (const float*)d_in[7];
  const float* Wn1 = (const float*)d_in[8];
  const float* bn1 = (const float*)d_in[9];
  const float* lng = (const float*)d_in[10];
  const float* lnb = (const float*)d_in[11];
  const float* Wn2 = (const float*)d_in[12];
  const float* bn2 = (const float*)d_in[13];

  float* num_g = (float*)d_ws;
  float* den_g = num_g + (size_t)NTOT * 64;

  hipMemsetAsync(d_ws, 0, (size_t)NTOT * 64 * 2 * sizeof(float), stream);
  edge_kernel<<<dim3((NTOT / 64) * MSPLIT), dim3(256), 0, stream>>>(
      h_l, x_l, h_r, x_r, W1, b1, W2, b2, num_g, den_g);
  node_kernel<<<dim3(NTOT / NODE_ROWS), dim3(256), 0, stream>>>(
      h_l, num_g, den_g, Wn1, bn1, lng, lnb, Wn2, bn2, (float*)d_out);
}

// Round 3
// 256.798 us; speedup vs baseline: 1.0408x; 1.0408x over previous
//
#include <hip/hip_runtime.h>
#include <hip/hip_bf16.h>
#include <hip/hip_fp16.h>

// INPUTS/OUTPUT ARE FLOAT32 (R1/R3/R4 NaN'd reading them as bf16).
// R19: trans+VALU SERIALIZE at issue (R16 edge time == sum of 16cyc/trans +
//      VALU cycles; R18's trans->f32-VALU move regressed). Objective is
//      minimize 16*T + V. Keep exp2 on trans (T=33/iter), move EVERYTHING
//      downstream to packed f16 (v_pk_*_f16 = 2cyc/2vals, the only vector
//      class with a real rate advantage; pk_f32 is 4cyc = no gain):
//      - abs-form sigmoid: E=2^(-|q|) in [0,1], d=1+E in [1,2] -> fits f16,
//        NaN impossible by construction (R18's safety, R16's cost).
//      - rcp: linear seed 24/17 - 8/17*d (1 pk_fma) + 2 Newton (4 pk ops)
//        = 10 cyc/pair, all f16.
//      - sign restore: one v_bfi_b32 on the PACKED reg (2 values at once).
//      - layer-1 preact in pk_f16 (6 cyc vs 12); silu result t16*sig16 IS
//        the A-frag word (old cvt_pkrtz pack eliminated).
//      Predict edge 147 -> ~125-135 us. If edge stays ~147: issue-block
//      model strict + boundary stalls eat V-savings -> all-VALU poly next.
// PERF NOTES (session summary):
//  - R5: forced low VGPR budget -> scratch spills, 2.6x slower. Keep (256,2).
//  - R11/R13/R16: three inner-loop mixes all ~145.5 us edge (issue floor
//    at that op mix: 65 trans/iter). R18: f32 NR rcp = +64 us (V inflation).
//  - Occupancy levers ALL exhausted; ~1.6 waves/SIMD real residency.
//  - Node/memset/launch overhead (~67 us) invariant to node restructure.

#define NTOT 2048
#define MTOT 2048
#define MSPLIT 32
#define MCHUNK 64   // == per-block m range: single staging chunk
#define NODE_ROWS 4 // rows per node block (1 per wave)

typedef _Float16 f16x8 __attribute__((ext_vector_type(8)));
typedef _Float16 f16x2 __attribute__((ext_vector_type(2)));
typedef float f32x4  __attribute__((ext_vector_type(4)));
typedef float f32x2  __attribute__((ext_vector_type(2)));
typedef int   i32x4  __attribute__((ext_vector_type(4)));

// exp(x) = 2^(x*log2e); sigmoid(x) = 1/(1+2^(-x*log2e))
#define L2E  (1.4426950408889634f)
#define NL2E (-1.4426950408889634f)
// exp(-d2/5) = 2^(d2 * -log2e/5)
#define C1E  (-0.2885390081777927f)

__device__ __forceinline__ float fast_exp2(float x) {
#if __has_builtin(__builtin_amdgcn_exp2f)
  return __builtin_amdgcn_exp2f(x);
#else
  return __exp2f(x);
#endif
}
__device__ __forceinline__ float fast_rcp(float x) {
#if __has_builtin(__builtin_amdgcn_rcpf)
  return __builtin_amdgcn_rcpf(x);
#else
  return 1.0f / x;
#endif
}
__device__ __forceinline__ float fast_rsq(float x) {
#if __has_builtin(__builtin_amdgcn_rsqf)
  return __builtin_amdgcn_rsqf(x);
#else
  return rsqrtf(x);
#endif
}
__device__ __forceinline__ f32x2 pk_fma(f32x2 a, f32x2 b, f32x2 c) {
  return __builtin_elementwise_fma(a, b, c);
}
__device__ __forceinline__ f16x2 pk_fma16(f16x2 a, f16x2 b, f16x2 c) {
  return __builtin_elementwise_fma(a, b, c);
}
// two f32 -> packed f16 pair (v_cvt_pkrtz_f16_f32, 1 instr)
__device__ __forceinline__ f16x2 cvt216(float lo, float hi) {
  return __builtin_bit_cast(f16x2, __builtin_amdgcn_cvt_pkrtz(lo, hi));
}

// sigmoid core in packed f16, given e16 = 2^(-|q|) in [0,1] and sign source
// sgn16 (sign(q) == sign of the sigmoid argument):
//   d = 1+e in [1,2]; r = 1/d via linear seed + 2 pk NR; result
//   sig = 0.5 + copysign(r-0.5, sgn). All pk_f16; NaN-free by construction.
__device__ __forceinline__ f16x2 sig16_core(f16x2 e16, f16x2 sgn16) {
  const f16x2 one16  = {(_Float16)1.f, (_Float16)1.f};
  const f16x2 two16  = {(_Float16)2.f, (_Float16)2.f};
  const f16x2 half16 = {(_Float16)0.5f, (_Float16)0.5f};
  const f16x2 c0_16  = {(_Float16)(24.f / 17.f), (_Float16)(24.f / 17.f)};
  const f16x2 c1_16  = {(_Float16)(-8.f / 17.f), (_Float16)(-8.f / 17.f)};
  const f16x2 dd = e16 + one16;              // [1,2] always
  f16x2 g = pk_fma16(dd, c1_16, c0_16);      // seed, <=5.9% rel err
  g = g * pk_fma16(-dd, g, two16);           // NR1
  g = g * pk_fma16(-dd, g, two16);           // NR2 -> ~f16 eps
  const unsigned mu = __builtin_bit_cast(unsigned, g - half16);
  const unsigned su = (mu & 0x7FFF7FFFu) |
                      (__builtin_bit_cast(unsigned, sgn16) & 0x80008000u);
  return __builtin_bit_cast(f16x2, su) + half16;
}

// ---------------------------------------------------------------------------
// Edge phase: per wave, 16 n-rows; loop over this block's 64-m range.
// dist-arg via d2 expansion; layer1+silu in packed f16; A-frag words come out
// of the silu mul directly; mfma_16x16x32_f16; sigmoid packed f16; f32
// accumulate; atomicAdd partials. Grid: (NTOT/64)*MSPLIT = 1024 blocks of 256.
// ---------------------------------------------------------------------------
__global__ __launch_bounds__(256, 2)
void edge_kernel(const float* __restrict__ h_l,
                 const float* __restrict__ x_l,
                 const float* __restrict__ h_r,
                 const float* __restrict__ x_r,
                 const float* __restrict__ W1,
                 const float* __restrict__ b1,
                 const float* __restrict__ W2,
                 const float* __restrict__ b2,
                 float* __restrict__ num_g,
                 float* __restrict__ den_g) {
  // hrT[ms][l15*4 + c] = h_r[m][c*16 + l15]  (per-lane float4 -> ds_read_b128)
  __shared__ float hrT[MCHUNK][64];   // 16 KB
  // xr_s[ms] = {xrC0, xrC1, xrC2, srC, rp0, rp1, rp2, pad}
  __shared__ float xr_s[MCHUNK][8];   // 2 KB

  const int tid  = threadIdx.x;
  const int wave = tid >> 6;
  const int lane = tid & 63;
  const int l15  = lane & 15;
  const int quad = lane >> 4;

  const int nblk   = blockIdx.x / MSPLIT;
  const int msplit = blockIdx.x % MSPLIT;
  const int n0     = nblk * 64 + wave * 16;
  const int mBase  = msplit * MCHUNK;

  // per-lane A-row n
  const int nA = n0 + l15;
  const float xl0 = x_l[nA * 3 + 0];
  const float xl1 = x_l[nA * 3 + 1];
  const float xl2 = x_l[nA * 3 + 2];
  const float slC = fmaf(xl2, xl2, fmaf(xl1, xl1, xl0 * xl0)) * C1E;
  const float lp0 = h_l[nA * 64 + 61];
  const float lp1 = h_l[nA * 64 + 62];
  const float lp2 = h_l[nA * 64 + 63];

  // layer-1 weights packed f16 pairs over j (this lane's 16 h1 cols:
  // h1 = quad*8 + j for j<8, 32 + quad*8 + (j-8) for j>=8)
  f16x2 w1d16[8], w1h16[8], w1y16[8], b116[8];
#pragma unroll
  for (int p = 0; p < 8; ++p) {
    const int j0 = 2 * p, j1 = 2 * p + 1;
    const int hA = (j0 < 8) ? (quad * 8 + j0) : (32 + quad * 8 + (j0 - 8));
    const int hB = (j1 < 8) ? (quad * 8 + j1) : (32 + quad * 8 + (j1 - 8));
    w1d16[p] = cvt216(W1[0 * 64 + hA], W1[0 * 64 + hB]);
    w1h16[p] = cvt216(W1[1 * 64 + hA], W1[1 * 64 + hB]);
    w1y16[p] = cvt216(W1[2 * 64 + hA], W1[2 * 64 + hB]);
    // edge_raw[3] == 1 -> fold W1 row 3 into bias
    b116[p] = cvt216(b1[hA] + W1[3 * 64 + hA], b1[hB] + W1[3 * 64 + hB]);
  }

  // W2 B-frags (f16): B[k = half*32 + quad*8 + j][col = c*16 + l15]
  f16x8 Bfrag[4][2];
#pragma unroll
  for (int c = 0; c < 4; ++c) {
#pragma unroll
    for (int h = 0; h < 2; ++h) {
      f16x8 f;
#pragma unroll
      for (int j = 0; j < 8; ++j) {
        const int k = h * 32 + quad * 8 + j;
        f[j] = (_Float16)W2[k * 64 + c * 16 + l15];
      }
      Bfrag[c][h] = f;
    }
  }

  // sigmoid fold: q = (acc + b2)*log2e  ->  q = acc*L2E + b2*L2E
  f32x2 b2l2[4];
#pragma unroll
  for (int c = 0; c < 4; ++c) {
    const float v = L2E * b2[c * 16 + l15];
    b2l2[c] = f32x2{v, v};
  }

  // stage h_r chunk (transposed groups of 4) + precomputed xr terms
  for (int idx = tid; idx < MCHUNK * 64; idx += 256) {
    const int mm = idx >> 6, w = idx & 63;
    const int i = w >> 2, c = w & 3;
    hrT[mm][w] = h_r[(mBase + mm) * 64 + c * 16 + i];
  }
  if (tid < MCHUNK) {
    const int m = mBase + tid;
    const float a0 = x_r[m * 3 + 0], a1 = x_r[m * 3 + 1], a2 = x_r[m * 3 + 2];
    const float r0 = h_r[m * 64 + 61], r1 = h_r[m * 64 + 62], r2 = h_r[m * 64 + 63];
    xr_s[tid][0] = a0 * (-2.0f * C1E);
    xr_s[tid][1] = a1 * (-2.0f * C1E);
    xr_s[tid][2] = a2 * (-2.0f * C1E);
    xr_s[tid][3] = fmaf(a2, a2, fmaf(a1, a1, a0 * a0)) * C1E;
    xr_s[tid][4] = r0;
    xr_s[tid][5] = r1;
    xr_s[tid][6] = r2;
    xr_s[tid][7] = 0.f;
  }

  const f32x4 zero4 = {0.f, 0.f, 0.f, 0.f};
  const f32x2 l2e2 = {L2E, L2E};
  const f16x2 l2e16 = {(_Float16)L2E, (_Float16)L2E};
  f32x2 numr2[4][2], denr2[4][2];
#pragma unroll
  for (int c = 0; c < 4; ++c)
#pragma unroll
    for (int h = 0; h < 2; ++h) {
      numr2[c][h] = f32x2{0.f, 0.f};
      denr2[c][h] = f32x2{0.f, 0.f};
    }

  __syncthreads();

#pragma unroll 2
  for (int ms = 0; ms < MCHUNK; ++ms) {
    // dist = exp2(C1E*(|xl|^2 + |xr|^2 - 2 xl.xr)) — 4 slots + exp
    const f32x4 xa = *(const f32x4*)&xr_s[ms][0];   // xrC0 xrC1 xrC2 srC
    const f32x4 xb = *(const f32x4*)&xr_s[ms][4];   // rp0 rp1 rp2 pad
    const float arg = fmaf(xl0, xa[0], fmaf(xl1, xa[1], fmaf(xl2, xa[2], slC + xa[3])));
    const float dist = fast_exp2(arg);
    const float hb = fmaf(lp0, xb[1], lp1 * xb[0]);
    const float hy = lp2 * xb[2];
    const f16x2 d16b  = cvt216(dist, dist);
    const f16x2 hb16b = cvt216(hb, hb);
    const f16x2 hy16b = cvt216(hy, hy);

    // layer 1 + silu, packed f16. q = t*log2e (sign(q)==sign(t));
    // e = 2^(-|q|) (trans, neg folded); sig via f16 NR; s = t*sig = A-frag.
    unsigned sw[8];
#pragma unroll
    for (int p = 0; p < 8; ++p) {
      const f16x2 t16 = pk_fma16(d16b, w1d16[p],
                        pk_fma16(hb16b, w1h16[p],
                        pk_fma16(hy16b, w1y16[p], b116[p])));
      const f16x2 q16 = t16 * l2e16;
      const unsigned au = __builtin_bit_cast(unsigned, q16) & 0x7FFF7FFFu;
      const f16x2 a16 = __builtin_bit_cast(f16x2, au);
      const float e0 = fast_exp2(-(float)a16.x);
      const float e1 = fast_exp2(-(float)a16.y);
      const f16x2 sg = sig16_core(cvt216(e0, e1), t16);
      const f16x2 s16 = t16 * sg;
      sw[p] = __builtin_bit_cast(unsigned, s16);
    }
    const i32x4 p0 = {(int)sw[0], (int)sw[1], (int)sw[2], (int)sw[3]};
    const i32x4 p1 = {(int)sw[4], (int)sw[5], (int)sw[6], (int)sw[7]};
    const f16x8 A0 = __builtin_bit_cast(f16x8, p0);
    const f16x8 A1 = __builtin_bit_cast(f16x8, p1);

    f32x4 acc[4];
#pragma unroll
    for (int c = 0; c < 4; ++c) {
      acc[c] = __builtin_amdgcn_mfma_f32_16x16x32_f16(A0, Bfrag[c][0], zero4, 0, 0, 0);
      acc[c] = __builtin_amdgcn_mfma_f32_16x16x32_f16(A1, Bfrag[c][1], acc[c], 0, 0, 0);
    }

    // sigmoid (packed f16 core) + f32 accumulate.
    // lane holds e[n = n0+quad*4+r][h2 = c*16+l15]; hrv per c via one b128.
    const f32x4 hrv4 = *(const f32x4*)&hrT[ms][l15 * 4];
#pragma unroll
    for (int c = 0; c < 4; ++c) {
      const f32x2 hrv2 = {hrv4[c], hrv4[c]};
#pragma unroll
      for (int h = 0; h < 2; ++h) {
        const f32x2 a2 = {acc[c][2 * h], acc[c][2 * h + 1]};
        const f32x2 qz = pk_fma(a2, l2e2, b2l2[c]);  // sign(qz)==sign(v)
        const float e0 = fast_exp2(-__builtin_fabsf(qz.x));
        const float e1 = fast_exp2(-__builtin_fabsf(qz.y));
        const f16x2 sgn16 = cvt216(qz.x, qz.y);
        const f16x2 sg = sig16_core(cvt216(e0, e1), sgn16);
        const f32x2 w2 = {(float)sg.x, (float)sg.y};
        numr2[c][h] = pk_fma(w2, hrv2, numr2[c][h]);
        denr2[c][h] = denr2[c][h] + w2;
      }
    }
  }

#pragma unroll
  for (int c = 0; c < 4; ++c)
#pragma unroll
    for (int h = 0; h < 2; ++h)
#pragma unroll
      for (int k = 0; k < 2; ++k) {
        const int r = 2 * h + k;
        const int n = n0 + quad * 4 + r;
        const int h2 = c * 16 + l15;
        atomicAdd(&num_g[n * 64 + h2], k ? numr2[c][h].y : numr2[c][h].x);
        atomicAdd(&den_g[n * 64 + h2], k ? denr2[c][h].y : denr2[c][h].x);
      }
}

// ---------------------------------------------------------------------------
// Node phase: NODE_ROWS rows per block (wave-local, no inner barriers).
// h_agg = num/(den+1e-6); z = cat(h_l,h_agg)@Wn1 + bn1 -> LN -> silu ->
// @Wn2 + bn2; out = h_l + z. Grid: NTOT/NODE_ROWS blocks of 256.
// ---------------------------------------------------------------------------
__global__ __launch_bounds__(256)
void node_kernel(const float* __restrict__ h_l,
                 const float* __restrict__ num_g,
                 const float* __restrict__ den_g,
                 const float* __restrict__ Wn1,
                 const float* __restrict__ bn1,
                 const float* __restrict__ ln_g,
                 const float* __restrict__ ln_b,
                 const float* __restrict__ Wn2,
                 const float* __restrict__ bn2,
                 float* __restrict__ out) {
  __shared__ float Wn1_s[128 * 64];
  __shared__ float Wn2_s[64 * 64];
  __shared__ float xbuf[4][128];
  __shared__ float zbuf[4][64];

  const int tid = threadIdx.x;
  for (int i = tid; i < 128 * 64; i += 256) Wn1_s[i] = Wn1[i];
  for (int i = tid; i < 64 * 64; i += 256) Wn2_s[i] = Wn2[i];

  const int wave = tid >> 6, lane = tid & 63;

  __syncthreads();

#pragma unroll 1
  for (int it = 0; it < NODE_ROWS / 4; ++it) {
    const int row = blockIdx.x * NODE_ROWS + it * 4 + wave;

    const float hl = h_l[row * 64 + lane];
    const float dn = den_g[row * 64 + lane] + 1e-6f;
    const float hagg = num_g[row * 64 + lane] * fast_rcp(dn);
    xbuf[wave][lane] = hl;
    xbuf[wave][64 + lane] = hagg;

    float t = bn1[lane];
#pragma unroll 8
    for (int k = 0; k < 128; ++k) t = fmaf(xbuf[wave][k], Wn1_s[k * 64 + lane], t);

    float s1 = t, s2 = t * t;
#pragma unroll
    for (int off = 32; off; off >>= 1) {
      s1 += __shfl_xor(s1, off);
      s2 += __shfl_xor(s2, off);
    }
    const float mu = s1 * 0.015625f;
    const float var = fmaf(s2, 0.015625f, -mu * mu);
    const float rs = fast_rsq(var + 1e-5f);
    const float zn = fmaf((t - mu) * rs, ln_g[lane], ln_b[lane]);
    const float sz = zn * fast_rcp(1.0f + fast_exp2(zn * NL2E));  // silu
    zbuf[wave][lane] = sz;

    float o = bn2[lane];
#pragma unroll 8
    for (int k = 0; k < 64; ++k) o = fmaf(zbuf[wave][k], Wn2_s[k * 64 + lane], o);

    out[row * 64 + lane] = hl + o;
  }
}

extern "C" void kernel_launch(void* const* d_in, const int* in_sizes, int n_in,
                              void* d_out, int out_size, void* d_ws, size_t ws_size,
                              hipStream_t stream) {
  const float* h_l = (const float*)d_in[0];
  const float* x_l = (const float*)d_in[1];
  const float* h_r = (const float*)d_in[2];
  const float* x_r = (const float*)d_in[3];
  const float* W1  = (const float*)d_in[4];
  const float* b1  = (const float*)d_in[5];
  const float* W2  = (const float*)d_in[6];
  const float* b2  = (const float*)d_in[7];
  const float* Wn1 = (const float*)d_in[8];
  const float* bn1 = (const float*)d_in[9];
  const float* lng = (const float*)d_in[10];
  const float* lnb = (const float*)d_in[11];
  const float* Wn2 = (const float*)d_in[12];
  const float* bn2 = (const float*)d_in[13];

  float* num_g = (float*)d_ws;
  float* den_g = num_g + (size_t)NTOT * 64;

  hipMemsetAsync(d_ws, 0, (size_t)NTOT * 64 * 2 * sizeof(float), stream);
  edge_kernel<<<dim3((NTOT / 64) * MSPLIT), dim3(256), 0, stream>>>(
      h_l, x_l, h_r, x_r, W1, b1, W2, b2, num_g, den_g);
  node_kernel<<<dim3(NTOT / NODE_ROWS), dim3(256), 0, stream>>>(
      h_l, num_g, den_g, Wn1, bn1, lng, lnb, Wn2, bn2, (float*)d_out);
}